// Round 5
// baseline (107.283 us; speedup 1.0000x reference)
//
#include <hip/hip_runtime.h>
#include <math.h>

// Problem constants (from reference setup_inputs): B=4, N=M=8192, fp32, SCALE=1.0
#define BATCH   4
#define NPTS    8192
#define THREADS 256
#define NQ      (2 * BATCH * NPTS)   // 65536 query slots (dir-major)

static constexpr float SCALE = 1.0f;

// d_ws layout: pm[TCH][NQ]  (chunk-major -> coalesced stores in k1 AND
// coalesced loads in k2), then float acc[2] + uint ticket (zeroed by k1).

// Kernel 1: per (dir, batch, query-tile, target-chunk) block.
// LDS holds CHUNK targets as float4(-2x, -2y, -2z, ||t||^2).
// Per distance: 3 FMA + amortized min3. ||q||^2 added in epilogue.
template<int TCH, int QPT>
__global__ __launch_bounds__(THREADS, 8)
void chamfer_min_kernel(const float* __restrict__ p1,
                        const float* __restrict__ p2,
                        float* __restrict__ pm,
                        float* __restrict__ acc)
{
    constexpr int CHUNK  = NPTS / TCH;        // targets staged per block
    constexpr int QPB    = THREADS * QPT;
    constexpr int QTILES = NPTS / QPB;

    // Zero the fused-reduction accumulators (ws is poisoned before every
    // call; k2 only runs after ALL k1 blocks complete -> no race).
    if (blockIdx.x == 0 && threadIdx.x < 3) acc[threadIdx.x] = 0.0f;

    __shared__ float4 lds4[CHUNK];            // 2 KB at TCH=64

    const int bid = blockIdx.x;               // 2048 blocks
    const int c   = bid % TCH;                           // target chunk
    const int qt  = (bid / TCH) % QTILES;                // query tile
    const int b   = (bid / (TCH * QTILES)) % BATCH;      // batch
    const int dir = bid / (TCH * QTILES * BATCH);        // 0:q=p1 1:q=p2

    const float* qptr = (dir == 0 ? p1 : p2) + (size_t)b * NPTS * 3;
    const float* tptr = (dir == 0 ? p2 : p1) + (size_t)b * NPTS * 3;

    // Stage targets -> LDS as (-2x, -2y, -2z, bb).
    const float* tsrc = tptr + (size_t)c * CHUNK * 3;
    for (int i = threadIdx.x; i < CHUNK; i += THREADS) {
        const float x = tsrc[3 * i + 0] * SCALE;
        const float y = tsrc[3 * i + 1] * SCALE;
        const float z = tsrc[3 * i + 2] * SCALE;
        const float bb = fmaf(z, z, fmaf(y, y, x * x));
        lds4[i] = make_float4(-2.0f * x, -2.0f * y, -2.0f * z, bb);
    }

    // QPT query points per thread (registers).
    const int t  = threadIdx.x;
    const int q0 = qt * QPB + t;
    float qx[QPT], qy[QPT], qz[QPT], qmin[QPT];
    #pragma unroll
    for (int k = 0; k < QPT; ++k) {
        const int q = q0 + k * THREADS;
        qx[k] = qptr[q * 3 + 0] * SCALE;
        qy[k] = qptr[q * 3 + 1] * SCALE;
        qz[k] = qptr[q * 3 + 2] * SCALE;
        qmin[k] = 3.0e38f;
    }

    __syncthreads();

    // Main loop: 8 targets/iter, uniform (broadcast) LDS reads,
    // 2*QPT independent 3-FMA chains per 2-target group.
    for (int j = 0; j < CHUNK; j += 8) {
        #pragma unroll
        for (int i = 0; i < 8; i += 2) {
            const float4 t0 = lds4[j + i];
            const float4 t1 = lds4[j + i + 1];
            #pragma unroll
            for (int k = 0; k < QPT; ++k) {
                float s0 = fmaf(qx[k], t0.x, t0.w);
                s0 = fmaf(qy[k], t0.y, s0);
                s0 = fmaf(qz[k], t0.z, s0);
                float s1 = fmaf(qx[k], t1.x, t1.w);
                s1 = fmaf(qy[k], t1.y, s1);
                s1 = fmaf(qz[k], t1.z, s1);
                qmin[k] = fminf(qmin[k], fminf(s0, s1));  // -> v_min3
            }
        }
    }

    // Epilogue: add ||q||^2 (monotone shift, commutes with chunk-min).
    // Chunk-major pm: consecutive lanes -> consecutive floats (coalesced).
    #pragma unroll
    for (int k = 0; k < QPT; ++k) {
        const float aa = fmaf(qz[k], qz[k], fmaf(qy[k], qy[k], qx[k] * qx[k]));
        const int q = q0 + k * THREADS;
        pm[(size_t)c * NQ + (size_t)(dir * BATCH + b) * NPTS + q] = qmin[k] + aa;
    }
}

// Kernel 2 (fused reduce + finalize): per-query min over TCH chunk
// partials (coalesced: lane idx consecutive per c), clamp, block sum,
// atomicAdd into acc[dir]; last block (ticket) writes the final scalar.
template<int TCH>
__global__ __launch_bounds__(512)
void chamfer_reduce_kernel(const float* __restrict__ pm,
                           float* __restrict__ acc,
                           float* __restrict__ out)
{
    const int idx = blockIdx.x * 512 + threadIdx.x;  // 0..65535
    float m = 3.0e38f;
    #pragma unroll
    for (int c = 0; c < TCH; ++c)
        m = fminf(m, pm[(size_t)c * NQ + idx]);
    m = fmaxf(m, 0.0f);   // reference's max(d, 0), commutes with min

    #pragma unroll
    for (int o = 32; o > 0; o >>= 1) m += __shfl_down(m, o, 64);

    __shared__ float red[8];
    const int wave = threadIdx.x >> 6;
    const int lane = threadIdx.x & 63;
    if (lane == 0) red[wave] = m;
    __syncthreads();
    if (threadIdx.x == 0) {
        float s = 0.0f;
        #pragma unroll
        for (int w = 0; w < 8; ++w) s += red[w];
        atomicAdd(&acc[blockIdx.x >> 6], s);     // blocks 0..63 dir0, rest dir1
        __threadfence();
        const unsigned tk = atomicAdd(reinterpret_cast<unsigned*>(acc + 2), 1u);
        if (tk == 127) {                          // last block of 128
            __threadfence();
            const float s0 = atomicAdd(&acc[0], 0.0f);  // atomic read
            const float s1 = atomicAdd(&acc[1], 0.0f);
            out[0] = (s0 + s1) * (1.0f / (float)(BATCH * NPTS));
        }
    }
}

template<int TCH, int QPT>
static void launch_all(const float* p1, const float* p2, float* out,
                       void* d_ws, hipStream_t stream)
{
    constexpr int QTILES = NPTS / (THREADS * QPT);
    float* pm  = (float*)d_ws;
    float* acc = pm + (size_t)TCH * NQ;

    chamfer_min_kernel<TCH, QPT><<<2 * BATCH * QTILES * TCH, THREADS, 0, stream>>>(p1, p2, pm, acc);
    chamfer_reduce_kernel<TCH><<<128, 512, 0, stream>>>(pm, acc, out);
}

extern "C" void kernel_launch(void* const* d_in, const int* in_sizes, int n_in,
                              void* d_out, int out_size, void* d_ws, size_t ws_size,
                              hipStream_t stream) {
    const float* p1 = (const float*)d_in[0];
    const float* p2 = (const float*)d_in[1];
    float* out = (float*)d_out;

    // ws_size is constant across calls -> branch is graph-capture safe.
    const size_t need64 = (size_t)64 * NQ * sizeof(float) + 64;
    if (ws_size >= need64) {
        launch_all<64, 8>(p1, p2, out, d_ws, stream);  // 2048 blocks, 32 w/CU
    } else {
        launch_all<32, 4>(p1, p2, out, d_ws, stream);  // 8 MB fallback (R3 geom)
    }
}